// Round 4
// baseline (402.228 us; speedup 1.0000x reference)
//
#include <hip/hip_runtime.h>
#include <math.h>

// Problem constants
#define BATCH   8
#define QLEN    256
#define KLEN    2048
#define KDIM    512
#define ADIMC   512
#define NHEADS  4
#define DKH     128
#define CHUNKW  4

static constexpr float INV_SCALE = 0.04419417382415922f; // 1/sqrt(512)
static constexpr float EPSV = 1e-6f;

typedef __attribute__((ext_vector_type(8))) short bf16x8;
typedef __attribute__((ext_vector_type(4))) float f32x4;

__device__ __forceinline__ unsigned short f2bf(float f) {
    unsigned u = __builtin_bit_cast(unsigned, f);
    u += 0x7fffu + ((u >> 16) & 1u);   // round-to-nearest-even
    return (unsigned short)(u >> 16);
}

// Async global->LDS, 16 B per lane (wave-uniform base + lane*16 rule).
__device__ __forceinline__ void gload_lds16(const void* g, void* l) {
    __builtin_amdgcn_global_load_lds(
        (const __attribute__((address_space(1))) void*)g,
        (__attribute__((address_space(3))) void*)l, 16, 0, 0);
}

// ---------------------------------------------------------------------------
// Elementwise f32 -> bf16 cast (4 elems/thread)
// ---------------------------------------------------------------------------
__global__ __launch_bounds__(256) void cast_bf16(
    const float* __restrict__ x, unsigned short* __restrict__ y, int n4)
{
    int i = blockIdx.x * 256 + threadIdx.x;
    if (i < n4) {
        float4 v = ((const float4*)x)[i];
        ushort4 o;
        o.x = f2bf(v.x); o.y = f2bf(v.y); o.z = f2bf(v.z); o.w = f2bf(v.w);
        ((ushort4*)y)[i] = o;
    }
}

// ---------------------------------------------------------------------------
// Transpose-cast: W [512 x 512] (k-major rows) -> WT [512 x 512] bf16, WT[n][k]
// ---------------------------------------------------------------------------
__global__ __launch_bounds__(256) void transpose_cast(
    const float* __restrict__ W, unsigned short* __restrict__ WT)
{
    __shared__ float tile[32][33];
    const int tx = threadIdx.x;          // 0..31
    const int ty = threadIdx.y;          // 0..7
    const int k0 = blockIdx.y * 32, n0 = blockIdx.x * 32;
    #pragma unroll
    for (int i = 0; i < 32; i += 8)
        tile[ty + i][tx] = W[(size_t)(k0 + ty + i) * KDIM + n0 + tx];
    __syncthreads();
    #pragma unroll
    for (int i = 0; i < 32; i += 8)
        WT[(size_t)(n0 + ty + i) * KDIM + k0 + tx] = f2bf(tile[tx][ty + i]);
}

// ---------------------------------------------------------------------------
// Staged NT MFMA core: block computes 128x128 f32 tile of A[M,K] @ B[N,K]^T.
// 256 threads / 4 waves, each wave a 64x64 subtile.
// ---------------------------------------------------------------------------
template<int KSTEPS>
__device__ __forceinline__ void mfma_nt_staged(
    const unsigned short* __restrict__ A, const unsigned short* __restrict__ B,
    int lda, int ldb, int bm, int bn,
    unsigned short* AsLDS, unsigned short* BsLDS, f32x4 acc[4][4])
{
    const int t = threadIdx.x;
    const int wv = t >> 6, ln = t & 63;
    const int r = ln & 15, quad = ln >> 4;
    const int wm = (wv >> 1) * 64, wn = (wv & 1) * 64;
    const int srow = wv * 16 + (ln >> 2);
    const int scol = (ln & 3) * 8;

    for (int ks = 0; ks < KSTEPS; ++ks) {
        const int k0 = ks * 32;
        #pragma unroll
        for (int j = 0; j < 2; ++j) {
            gload_lds16(A + (size_t)(bm + j * 64 + srow) * lda + k0 + scol,
                        AsLDS + (size_t)(j * 64 + wv * 16) * 32);
            gload_lds16(B + (size_t)(bn + j * 64 + srow) * ldb + k0 + scol,
                        BsLDS + (size_t)(j * 64 + wv * 16) * 32);
        }
        __syncthreads();
        bf16x8 af[4], bg[4];
        #pragma unroll
        for (int f = 0; f < 4; ++f)
            af[f] = *(const bf16x8*)(AsLDS + (size_t)(wm + f * 16 + r) * 32 + quad * 8);
        #pragma unroll
        for (int f = 0; f < 4; ++f)
            bg[f] = *(const bf16x8*)(BsLDS + (size_t)(wn + f * 16 + r) * 32 + quad * 8);
        #pragma unroll
        for (int i = 0; i < 4; ++i)
            #pragma unroll
            for (int j2 = 0; j2 < 4; ++j2)
                acc[i][j2] = __builtin_amdgcn_mfma_f32_16x16x32_bf16(
                    af[i], bg[j2], acc[i][j2], 0, 0, 0);
        __syncthreads();
    }
}

__device__ __forceinline__ void zero_acc(f32x4 acc[4][4]) {
    #pragma unroll
    for (int i = 0; i < 4; ++i)
        #pragma unroll
        for (int j = 0; j < 4; ++j)
            acc[i][j] = f32x4{0.f, 0.f, 0.f, 0.f};
}

// ---------------------------------------------------------------------------
// Projection: C[M x 1024] bf16 = A[M x 512] @ WT[1024 x 512]^T + bias
// ---------------------------------------------------------------------------
__global__ __launch_bounds__(256) void proj_mfma(
    const unsigned short* __restrict__ A, const unsigned short* __restrict__ WT,
    const float* __restrict__ bias_m, const float* __restrict__ bias_c,
    unsigned short* __restrict__ C)
{
    __shared__ unsigned short As[128 * 32];
    __shared__ unsigned short Bs[128 * 32];
    const int bm = blockIdx.y * 128, bn = blockIdx.x * 128;
    f32x4 acc[4][4]; zero_acc(acc);
    mfma_nt_staged<16>(A, WT, KDIM, KDIM, bm, bn, As, Bs, acc);
    const int wv = threadIdx.x >> 6, ln = threadIdx.x & 63;
    const int r = ln & 15, quad = ln >> 4;
    const int m0 = bm + (wv >> 1) * 64, n0 = bn + (wv & 1) * 64;
    #pragma unroll
    for (int j = 0; j < 4; ++j) {
        const int n = n0 + j * 16 + r;
        const float bv = (n < 512) ? bias_m[n] : bias_c[n - 512];
        #pragma unroll
        for (int i = 0; i < 4; ++i) {
            #pragma unroll
            for (int reg = 0; reg < 4; ++reg) {
                const int m = m0 + i * 16 + quad * 4 + reg;
                C[(size_t)m * 1024 + n] = f2bf(acc[i][j][reg] + bv);
            }
        }
    }
}

// ---------------------------------------------------------------------------
// p_choose: per batch b, p = sigmoid(qm[b] @ km[b]^T / sqrt(512) + r + noise)
// ---------------------------------------------------------------------------
__global__ __launch_bounds__(256) void pchoose_mfma(
    const unsigned short* __restrict__ qp, const unsigned short* __restrict__ kp,
    const float* __restrict__ noise, const float* __restrict__ rp,
    float* __restrict__ p)
{
    __shared__ unsigned short As[128 * 32];
    __shared__ unsigned short Bs[128 * 32];
    const int b = blockIdx.z;
    const unsigned short* A = qp + (size_t)b * QLEN * 1024;
    const unsigned short* B = kp + (size_t)b * KLEN * 1024;
    const int bm = blockIdx.y * 128, bn = blockIdx.x * 128;
    f32x4 acc[4][4]; zero_acc(acc);
    mfma_nt_staged<16>(A, B, 1024, 1024, bm, bn, As, Bs, acc);
    const int wv = threadIdx.x >> 6, ln = threadIdx.x & 63;
    const int r = ln & 15, quad = ln >> 4;
    const int m0 = bm + (wv >> 1) * 64, n0 = bn + (wv & 1) * 64;
    const float rv = rp[0];
    #pragma unroll
    for (int i = 0; i < 4; ++i) {
        #pragma unroll
        for (int reg = 0; reg < 4; ++reg) {
            const int q = m0 + i * 16 + quad * 4 + reg;
            const size_t rowoff = ((size_t)b * QLEN + q) * KLEN;
            #pragma unroll
            for (int j = 0; j < 4; ++j) {
                const int k = n0 + j * 16 + r;
                const float e = acc[i][j][reg] * INV_SCALE + rv + noise[rowoff + k];
                p[rowoff + k] = __builtin_amdgcn_rcpf(1.0f + __expf(-e));
            }
        }
    }
}

// ---------------------------------------------------------------------------
// 64-lane inclusive prefix sum via DPP (≈6 VALU ops)
// ---------------------------------------------------------------------------
__device__ __forceinline__ float wave_incl_scan(float x)
{
#define DPP_ADD(ctrl, rmask, bctrl)                                            \
    { int _t = __builtin_amdgcn_update_dpp(0, __builtin_bit_cast(int, x),      \
                                           ctrl, rmask, 0xf, bctrl);           \
      x += __builtin_bit_cast(float, _t); }
    DPP_ADD(0x111, 0xf, true)   // row_shr:1
    DPP_ADD(0x112, 0xf, true)   // row_shr:2
    DPP_ADD(0x114, 0xf, true)   // row_shr:4
    DPP_ADD(0x118, 0xf, true)   // row_shr:8
    DPP_ADD(0x142, 0xa, false)  // row_bcast:15 -> rows 1,3
    DPP_ADD(0x143, 0xc, false)  // row_bcast:31 -> rows 2,3
#undef DPP_ADD
    return x;
}

// ---------------------------------------------------------------------------
// cumprod_mr: per (b,q) row: cp = exp(excl_cumsum(log(clip(1-p)))); emits
// m = p*cp, r = 1/clip(cp). Fast intrinsics; absorbs all transcendentals.
// ---------------------------------------------------------------------------
__global__ __launch_bounds__(256) void cumprod_mr(
    const float* __restrict__ p, float* __restrict__ mArr, float* __restrict__ rArr)
{
    const size_t row = blockIdx.x;
    const float* pr = p + row * KLEN;
    float* mr = mArr + row * KLEN;
    float* rr = rArr + row * KLEN;
    const int tid = threadIdx.x;
    const int lane = tid & 63, wid = tid >> 6;
    __shared__ float waveTot[4];

    float4 v0 = *(const float4*)(pr + tid * 8);
    float4 v1 = *(const float4*)(pr + tid * 8 + 4);
    float pv[8] = {v0.x, v0.y, v0.z, v0.w, v1.x, v1.y, v1.z, v1.w};
    float excl[8];
    float run = 0.0f;
    #pragma unroll
    for (int j = 0; j < 8; ++j) {
        float l = __logf(fminf(fmaxf(1.0f - pv[j], EPSV), 1.0f));
        excl[j] = run;
        run += l;
    }
    float s = wave_incl_scan(run);
    if (lane == 63) waveTot[wid] = s;
    __syncthreads();
    float wex = 0.0f;
    for (int w = 0; w < wid; ++w) wex += waveTot[w];
    const float texcl = wex + s - run;

    float mv[8], rv[8];
    #pragma unroll
    for (int j = 0; j < 8; ++j) {
        const float cpv = __expf(texcl + excl[j]);
        mv[j] = pv[j] * cpv;
        rv[j] = __builtin_amdgcn_rcpf(fminf(fmaxf(cpv, EPSV), 1.0f));
    }
    *(float4*)(mr + tid * 8)     = *(float4*)&mv[0];
    *(float4*)(mr + tid * 8 + 4) = *(float4*)&mv[4];
    *(float4*)(rr + tid * 8)     = *(float4*)&rv[0];
    *(float4*)(rr + tid * 8 + 4) = *(float4*)&rv[4];
}

// ---------------------------------------------------------------------------
// alpha_echunk: FUSED kernel.
//  Blocks 0..7: alpha recurrence as a SKEWED WAVE PIPELINE (no barriers).
//    R3 post-mortem: the 8-wave barrier step costs ~800 cyc intrinsically
//    (lgkmcnt drain + 8-wave s_barrier + LDS read-back), x256 steps = ~85us;
//    CU isolation only bought 4%. Dataflow fact: wave w's total T_w[i]
//    depends only on its own step-(i-1) state, NOT on the incoming prefix
//    P_{w-1}[i]. So waves form a forwarding chain: receive P_{w-1}[i],
//    publish P_w[i] = P_{w-1}[i] + T_w[i] (one add + one ds_write_b64).
//    The 7-hop propagation pipelines across steps (constant skew offset);
//    throughput = per-wave local work (~150-250 cyc/step modeled).
//    Sync: slots[256][8] u64 in LDS, unique slot per (step,wave) -> no
//    reuse/ABA. Producer lane63 writes ONE ds_write_b64 {P lo, flag=i+1 hi}
//    (single-instruction adjacent-bank write; flag validates data within
//    the same b64 read). Consumers poll with a volatile b64 broadcast read
//    (same addr all lanes = conflict-free), issued at step start so its
//    ~130cy latency hides under the chain+scan. One __syncthreads total
//    (flag init). Arithmetic identical to R0/R3.
//  Blocks 8..1031: e_chunk MFMA tiles (unchanged; fill the idle CUs).
//  smem stays 96 KB -> 1 block/CU (R3 isolation, kept).
// ---------------------------------------------------------------------------
__global__ __launch_bounds__(512, 1) void alpha_echunk(
    const float* __restrict__ mArr, const float* __restrict__ rArr,
    float* __restrict__ alpha,
    const unsigned short* __restrict__ qp, const unsigned short* __restrict__ kp,
    float* __restrict__ out)
{
    __shared__ __align__(16) char smem[98304];   // 96 KB -> 1 block/CU
    const int bid = blockIdx.x;
    const int tid = threadIdx.x;

    if (bid < BATCH) {
        // -------- alpha scan: skewed wave pipeline, barrier-free --------
        unsigned long long* slots = (unsigned long long*)smem;   // [256][8]
        for (int idx = tid; idx < QLEN * 8; idx += 512) slots[idx] = 0ULL;
        __syncthreads();                 // the ONLY block barrier

        __builtin_amdgcn_s_setprio(1);
        const int lane = tid & 63, wid = tid >> 6;
        const float* mrow = mArr + (size_t)bid * QLEN * KLEN + tid * 4;
        const float* rrow = rArr + (size_t)bid * QLEN * KLEN + tid * 4;
        float* arow = alpha + (size_t)bid * QLEN * KLEN + tid * 4;

        // poll source (wave w-1's slot) and publish target (own slot)
        volatile unsigned long long* psl  = slots + ((wid > 0) ? (wid - 1) : 0);
        volatile unsigned long long* pslw = slots + wid;

        float aw0 = 0.f, aw1 = 0.f, aw2 = 0.f, aw3 = 0.f;
        if (tid == 0) aw0 = 1.0f;   // aw_prev one-hot at k=0

        float4 mA = *(const float4*)(mrow);
        float4 rA = *(const float4*)(rrow);
        float4 mB = *(const float4*)(mrow + KLEN);
        float4 rB = *(const float4*)(rrow + KLEN);

#define ASTEP(I, MREG, RREG)                                                   \
    {                                                                          \
        const int i_ = (I);                                                    \
        unsigned long long v_ = 0ULL;                                          \
        if (wid > 0) v_ = *psl;          /* early issue: hide LDS latency */   \
        float4 mc = MREG, rc = RREG;                                           \
        const int rn_ = (i_ + 2 < QLEN) ? (i_ + 2) : (QLEN - 1);               \
        MREG = *(const float4*)(mrow + (size_t)rn_ * KLEN);                    \
        RREG = *(const float4*)(rrow + (size_t)rn_ * KLEN);                    \
        float run = 0.0f, i0, i1, i2, i3;                                      \
        run = fmaf(aw0, rc.x, run); i0 = run;                                  \
        run = fmaf(aw1, rc.y, run); i1 = run;                                  \
        run = fmaf(aw2, rc.z, run); i2 = run;                                  \
        run = fmaf(aw3, rc.w, run); i3 = run;                                  \
        float s_ = wave_incl_scan(run);                                        \
        float base = 0.0f;                                                     \
        if (wid > 0) {                                                         \
            while ((unsigned)(v_ >> 32) != (unsigned)(i_ + 1)) v_ = *psl;      \
            base = __builtin_bit_cast(float, (unsigned)v_);                    \
        }                                                                      \
        if (wid < 7 && lane == 63)                                             \
            *pslw = ((unsigned long long)(unsigned)(i_ + 1) << 32)             \
                  | (unsigned long long)__builtin_bit_cast(unsigned, base + s_);\
        psl += 8; pslw += 8;                                                   \
        const float wb = base + (s_ - run);                                    \
        aw0 = mc.x * (wb + i0);                                                \
        aw1 = mc.y * (wb + i1);                                                \
        aw2 = mc.z * (wb + i2);                                                \
        aw3 = mc.w * (wb + i3);                                                \
        float4 ov; ov.x = aw0; ov.y = aw1; ov.z = aw2; ov.w = aw3;             \
        *(float4*)(arow + (size_t)i_ * KLEN) = ov;                             \
    }

        for (int io = 0; io < QLEN; io += 2) {
            ASTEP(io + 0, mA, rA)
            ASTEP(io + 1, mB, rB)
        }
#undef ASTEP
        __builtin_amdgcn_s_setprio(0);
        return;
    }

    // ---------------- echunk tile ----------------
    const int v = bid - BATCH;           // 0..1023
    const int z = v >> 5;                // 0..31 = b*4+h
    const int by = (v >> 4) & 1;
    const int bx = v & 15;
    const int b = z >> 2, h = z & 3;
    const bool worker = tid < 256;
    unsigned short* As = (unsigned short*)smem;            // 8 KB
    unsigned short* Bs = (unsigned short*)(smem + 8192);   // 8 KB
    const unsigned short* A = qp + (size_t)b * QLEN * 1024 + 512 + h * DKH;
    const unsigned short* B = kp + (size_t)b * KLEN * 1024 + 512 + h * DKH;
    const int bm = by * 128, bn = bx * 128;

    const int wv = tid >> 6, ln = tid & 63;
    const int r = ln & 15, quad = ln >> 4;
    const int wm = (wv >> 1) * 64, wn = (wv & 1) * 64;
    const int srow = (wv & 3) * 16 + (ln >> 2);
    const int scol = (ln & 3) * 8;

    f32x4 acc[4][4]; zero_acc(acc);
    for (int ks = 0; ks < 4; ++ks) {
        const int k0 = ks * 32;
        if (worker) {
            #pragma unroll
            for (int j = 0; j < 2; ++j) {
                gload_lds16(A + (size_t)(bm + j * 64 + srow) * 1024 + k0 + scol,
                            As + (size_t)(j * 64 + wv * 16) * 32);
                gload_lds16(B + (size_t)(bn + j * 64 + srow) * 1024 + k0 + scol,
                            Bs + (size_t)(j * 64 + wv * 16) * 32);
            }
        }
        __syncthreads();
        if (worker) {
            bf16x8 af[4], bg[4];
            #pragma unroll
            for (int f = 0; f < 4; ++f)
                af[f] = *(const bf16x8*)(As + (size_t)(wm + f * 16 + r) * 32 + quad * 8);
            #pragma unroll
            for (int f = 0; f < 4; ++f)
                bg[f] = *(const bf16x8*)(Bs + (size_t)(wn + f * 16 + r) * 32 + quad * 8);
            #pragma unroll
            for (int i = 0; i < 4; ++i)
                #pragma unroll
                for (int j2 = 0; j2 < 4; ++j2)
                    acc[i][j2] = __builtin_amdgcn_mfma_f32_16x16x32_bf16(
                        af[i], bg[j2], acc[i][j2], 0, 0, 0);
        }
        __syncthreads();
    }
    if (worker) {
        const int m0 = bm + (wv >> 1) * 64, n0 = bn + (wv & 1) * 64;
        #pragma unroll
        for (int i = 0; i < 4; ++i) {
            #pragma unroll
            for (int reg = 0; reg < 4; ++reg) {
                const int q = m0 + i * 16 + quad * 4 + reg;
                const size_t rowoff = ((size_t)z * QLEN + q) * KLEN;
                #pragma unroll
                for (int j = 0; j < 4; ++j) {
                    const int k = n0 + j * 16 + r;
                    out[rowoff + k] = acc[i][j][reg] * INV_SCALE;
                }
            }
        }
    }
}

// ---------------------------------------------------------------------------
// beta: per (b,h,q) row of 2048 (e_chunk in d_out, overwritten)
// ---------------------------------------------------------------------------
__global__ __launch_bounds__(256) void beta_kernel(
    float* __restrict__ eo, const float* __restrict__ alpha)
{
    __shared__ float sse[KLEN + 3];
    __shared__ float su[KLEN + 3];
    __shared__ float wmax[4];

    const int tid = threadIdx.x;
    const int lane = tid & 63, wid = tid >> 6;
    const int row = blockIdx.x;                 // [B*H*Q]
    const int q = row & (QLEN - 1);
    const int b = row >> 10;
    float* erow = eo + (size_t)row * KLEN;
    const float* arow = alpha + ((size_t)b * QLEN + q) * KLEN;

    if (tid < 3) { sse[tid] = 0.0f; su[KLEN + tid] = 0.0f; }

    float ev[8];
    float lm = -INFINITY;
    #pragma unroll
    for (int j = 0; j < 8; ++j) {
        const int k = tid + 256 * j;
        ev[j] = erow[k];
        lm = fmaxf(lm, ev[j]);
    }
    #pragma unroll
    for (int off = 32; off > 0; off >>= 1) lm = fmaxf(lm, __shfl_xor(lm, off));
    if (lane == 0) wmax[wid] = lm;
    __syncthreads();
    const float mx = fmaxf(fmaxf(wmax[0], wmax[1]), fmaxf(wmax[2], wmax[3]));

    #pragma unroll
    for (int j = 0; j < 8; ++j) {
        const int k = tid + 256 * j;
        sse[k + 3] = fmaxf(__expf(ev[j] - mx), 1e-5f);
    }
    __syncthreads();

    #pragma unroll
    for (int j = 0; j < 8; ++j) {
        const int k = tid + 256 * j;
        const float denom = sse[k + 3] + sse[k + 2] + sse[k + 1] + sse[k];
        su[k] = arow[k] * __builtin_amdgcn_rcpf(denom);
    }
    __syncthreads();

    #pragma unroll
    for (int j = 0; j < 8; ++j) {
        const int k = tid + 256 * j;
        erow[k] = sse[k + 3] * (su[k] + su[k + 1] + su[k + 2] + su[k + 3]);
    }
}

// ---------------------------------------------------------------------------
extern "C" void kernel_launch(void* const* d_in, const int* in_sizes, int n_in,
                              void* d_out, int out_size, void* d_ws, size_t ws_size,
                              hipStream_t stream)
{
    (void)in_sizes; (void)n_in; (void)out_size; (void)ws_size;
    const float* key_enc = (const float*)d_in[0];   // [8,2048,512]
    const float* query   = (const float*)d_in[1];   // [8,256,512]
    const float* noise   = (const float*)d_in[2];   // [8,256,2048]
    const float* Wk_m    = (const float*)d_in[3];
    const float* bk_m    = (const float*)d_in[4];
    const float* Wq_m    = (const float*)d_in[5];
    const float* bq_m    = (const float*)d_in[6];
    const float* rp      = (const float*)d_in[7];
    const float* Wk_c    = (const float*)d_in[8];
    const float* bk_c    = (const float*)d_in[9];
    const float* Wq_c    = (const float*)d_in[10];
    const float* bq_c    = (const float*)d_in[11];
    float* out = (float*)d_out;                     // [8,4,256,2048]

    // workspace layout (bytes)
    char* w = (char*)d_ws;
    unsigned short* kx    = (unsigned short*)w; w += (size_t)BATCH * KLEN * KDIM * 2;   // 16.8 MB
    unsigned short* qx    = (unsigned short*)w; w += (size_t)BATCH * QLEN * KDIM * 2;   //  2.1 MB
    unsigned short* WTk   = (unsigned short*)w; w += (size_t)1024 * KDIM * 2;           //  1.0 MB
    unsigned short* WTq   = (unsigned short*)w; w += (size_t)1024 * KDIM * 2;           //  1.0 MB
    unsigned short* kproj = (unsigned short*)w; w += (size_t)BATCH * KLEN * 1024 * 2;   // 33.6 MB
    unsigned short* qproj = (unsigned short*)w; w += (size_t)BATCH * QLEN * 1024 * 2;   //  4.2 MB
    float* p_alpha = (float*)w; w += (size_t)BATCH * QLEN * KLEN * 4;                   // 16.8 MB
    float* mArr    = (float*)w; w += (size_t)BATCH * QLEN * KLEN * 4;                   // 16.8 MB
    float* rArr    = (float*)w;                                                         // 16.8 MB

    // 1) casts
    hipLaunchKernelGGL(cast_bf16, dim3(BATCH * KLEN * KDIM / 4 / 256), dim3(256), 0, stream,
                       key_enc, kx, BATCH * KLEN * KDIM / 4);
    hipLaunchKernelGGL(cast_bf16, dim3(BATCH * QLEN * KDIM / 4 / 256), dim3(256), 0, stream,
                       query, qx, BATCH * QLEN * KDIM / 4);
    hipLaunchKernelGGL(transpose_cast, dim3(16, 16), dim3(32, 8), 0, stream, Wk_m, WTk);
    hipLaunchKernelGGL(transpose_cast, dim3(16, 16), dim3(32, 8), 0, stream, Wk_c, WTk + (size_t)512 * KDIM);
    hipLaunchKernelGGL(transpose_cast, dim3(16, 16), dim3(32, 8), 0, stream, Wq_m, WTq);
    hipLaunchKernelGGL(transpose_cast, dim3(16, 16), dim3(32, 8), 0, stream, Wq_c, WTq + (size_t)512 * KDIM);

    // 2) projections (staged bf16 MFMA, fused bias, bf16 out)
    hipLaunchKernelGGL(proj_mfma, dim3(8, BATCH * KLEN / 128), dim3(256), 0, stream,
                       kx, WTk, bk_m, bk_c, kproj);
    hipLaunchKernelGGL(proj_mfma, dim3(8, BATCH * QLEN / 128), dim3(256), 0, stream,
                       qx, WTq, bq_m, bq_c, qproj);

    // 3) p_choose (staged bf16 MFMA + fast sigmoid epilogue)
    hipLaunchKernelGGL(pchoose_mfma, dim3(KLEN / 128, QLEN / 128, BATCH), dim3(256), 0, stream,
                       qproj, kproj, noise, rp, p_alpha);

    // 4) cumprod -> (m, r)  (parallel, absorbs all transcendentals)
    hipLaunchKernelGGL(cumprod_mr, dim3(BATCH * QLEN), dim3(256), 0, stream,
                       p_alpha, mArr, rArr);

    // 5) FUSED: alpha recurrence (blocks 0..7, skewed wave pipeline) +
    //           e_chunk (blocks 8..1031)
    hipLaunchKernelGGL(alpha_echunk, dim3(BATCH + KLEN / 128 * QLEN / 128 * BATCH * NHEADS),
                       dim3(512), 0, stream,
                       mArr, rArr, p_alpha, qproj, kproj, out);

    // 6) beta (overwrites e_chunk rows in d_out)
    hipLaunchKernelGGL(beta_kernel, dim3(BATCH * NHEADS * QLEN), dim3(256), 0, stream,
                       out, p_alpha);
}

// Round 5
// 296.646 us; speedup vs baseline: 1.3559x; 1.3559x over previous
//
#include <hip/hip_runtime.h>
#include <math.h>

// Problem constants
#define BATCH   8
#define QLEN    256
#define KLEN    2048
#define KDIM    512
#define ADIMC   512
#define NHEADS  4
#define DKH     128
#define CHUNKW  4

static constexpr float INV_SCALE = 0.04419417382415922f; // 1/sqrt(512)
static constexpr float EPSV = 1e-6f;

typedef __attribute__((ext_vector_type(8))) short bf16x8;
typedef __attribute__((ext_vector_type(4))) float f32x4;

__device__ __forceinline__ unsigned short f2bf(float f) {
    unsigned u = __builtin_bit_cast(unsigned, f);
    u += 0x7fffu + ((u >> 16) & 1u);   // round-to-nearest-even
    return (unsigned short)(u >> 16);
}

// Barrier waiting only on LDS ops (lgkmcnt); global loads/stores stay in flight.
__device__ __forceinline__ void lds_barrier() {
    __asm__ volatile("s_waitcnt lgkmcnt(0)\n\ts_barrier" ::: "memory");
}

// Async global->LDS, 16 B per lane (wave-uniform base + lane*16 rule).
__device__ __forceinline__ void gload_lds16(const void* g, void* l) {
    __builtin_amdgcn_global_load_lds(
        (const __attribute__((address_space(1))) void*)g,
        (__attribute__((address_space(3))) void*)l, 16, 0, 0);
}

// ---------------------------------------------------------------------------
// prep: fused input casts + weight transpose-casts (one launch instead of 6).
//  blocks [0, 8192)          : cast key_enc -> kx (bf16)
//  blocks [8192, 9216)       : cast query   -> qx (bf16)
//  blocks [9216, 10240)      : 4x transpose-cast W[512x512] -> WT bf16
// ---------------------------------------------------------------------------
#define NKXB (BATCH * KLEN * KDIM / 4 / 256)   // 8192
#define NQXB (BATCH * QLEN * KDIM / 4 / 256)   // 1024
__global__ __launch_bounds__(256) void prep(
    const float* __restrict__ key_enc, const float* __restrict__ query,
    const float* __restrict__ Wk_m, const float* __restrict__ Wk_c,
    const float* __restrict__ Wq_m, const float* __restrict__ Wq_c,
    unsigned short* __restrict__ kx, unsigned short* __restrict__ qx,
    unsigned short* __restrict__ WTk, unsigned short* __restrict__ WTq)
{
    __shared__ float tile[32][33];
    const int gb = blockIdx.x;
    const int tid = threadIdx.x;

    if (gb < NKXB + NQXB) {
        const float* x = (gb < NKXB) ? key_enc : query;
        unsigned short* y = (gb < NKXB) ? kx : qx;
        const int i = (gb < NKXB ? gb : gb - NKXB) * 256 + tid;
        float4 v = ((const float4*)x)[i];
        ushort4 o;
        o.x = f2bf(v.x); o.y = f2bf(v.y); o.z = f2bf(v.z); o.w = f2bf(v.w);
        ((ushort4*)y)[i] = o;
        return;
    }
    const int t = gb - NKXB - NQXB;          // 0..1023
    const int which = t >> 8;                // 0..3
    const int tt = t & 255;
    const int bx = tt & 15, byy = tt >> 4;   // 16 x 16 tile grid
    const float* W = (which == 0) ? Wk_m : (which == 1) ? Wk_c
                   : (which == 2) ? Wq_m : Wq_c;
    unsigned short* WT = (which == 0) ? WTk
                       : (which == 1) ? WTk + (size_t)512 * KDIM
                       : (which == 2) ? WTq : WTq + (size_t)512 * KDIM;
    const int tx = tid & 31, ty = tid >> 5;  // 32 x 8
    const int k0 = byy * 32, n0 = bx * 32;
    #pragma unroll
    for (int i = 0; i < 32; i += 8)
        tile[ty + i][tx] = W[(size_t)(k0 + ty + i) * KDIM + n0 + tx];
    __syncthreads();
    #pragma unroll
    for (int i = 0; i < 32; i += 8)
        WT[(size_t)(n0 + ty + i) * KDIM + k0 + tx] = f2bf(tile[tx][ty + i]);
}

// ---------------------------------------------------------------------------
// Staged NT MFMA core: block computes 128x128 f32 tile of A[M,K] @ B[N,K]^T.
// 256 threads / 4 waves, each wave a 64x64 subtile.
// ---------------------------------------------------------------------------
template<int KSTEPS>
__device__ __forceinline__ void mfma_nt_staged(
    const unsigned short* __restrict__ A, const unsigned short* __restrict__ B,
    int lda, int ldb, int bm, int bn,
    unsigned short* AsLDS, unsigned short* BsLDS, f32x4 acc[4][4])
{
    const int t = threadIdx.x;
    const int wv = t >> 6, ln = t & 63;
    const int r = ln & 15, quad = ln >> 4;
    const int wm = (wv >> 1) * 64, wn = (wv & 1) * 64;
    const int srow = wv * 16 + (ln >> 2);
    const int scol = (ln & 3) * 8;

    for (int ks = 0; ks < KSTEPS; ++ks) {
        const int k0 = ks * 32;
        #pragma unroll
        for (int j = 0; j < 2; ++j) {
            gload_lds16(A + (size_t)(bm + j * 64 + srow) * lda + k0 + scol,
                        AsLDS + (size_t)(j * 64 + wv * 16) * 32);
            gload_lds16(B + (size_t)(bn + j * 64 + srow) * ldb + k0 + scol,
                        BsLDS + (size_t)(j * 64 + wv * 16) * 32);
        }
        __syncthreads();
        bf16x8 af[4], bg[4];
        #pragma unroll
        for (int f = 0; f < 4; ++f)
            af[f] = *(const bf16x8*)(AsLDS + (size_t)(wm + f * 16 + r) * 32 + quad * 8);
        #pragma unroll
        for (int f = 0; f < 4; ++f)
            bg[f] = *(const bf16x8*)(BsLDS + (size_t)(wn + f * 16 + r) * 32 + quad * 8);
        #pragma unroll
        for (int i = 0; i < 4; ++i)
            #pragma unroll
            for (int j2 = 0; j2 < 4; ++j2)
                acc[i][j2] = __builtin_amdgcn_mfma_f32_16x16x32_bf16(
                    af[i], bg[j2], acc[i][j2], 0, 0, 0);
        __syncthreads();
    }
}

__device__ __forceinline__ void zero_acc(f32x4 acc[4][4]) {
    #pragma unroll
    for (int i = 0; i < 4; ++i)
        #pragma unroll
        for (int j = 0; j < 4; ++j)
            acc[i][j] = f32x4{0.f, 0.f, 0.f, 0.f};
}

// ---------------------------------------------------------------------------
// Projection (merged k+q): C[M x 1024] bf16 = A[M x 512] @ WT[1024 x 512]^T + b
//   blockIdx.y <  128 : kproj rows
//   blockIdx.y >= 128 : qproj rows (by-128)
// ---------------------------------------------------------------------------
__global__ __launch_bounds__(256) void proj_mfma(
    const unsigned short* __restrict__ kx, const unsigned short* __restrict__ qx,
    const unsigned short* __restrict__ WTk, const unsigned short* __restrict__ WTq,
    const float* __restrict__ bk_m, const float* __restrict__ bk_c,
    const float* __restrict__ bq_m, const float* __restrict__ bq_c,
    unsigned short* __restrict__ kproj, unsigned short* __restrict__ qproj)
{
    __shared__ unsigned short As[128 * 32];
    __shared__ unsigned short Bs[128 * 32];
    const int by = blockIdx.y;
    const unsigned short *A, *WT;
    unsigned short* C;
    const float *bm_, *bc_;
    int bm;
    if (by < 128) { A = kx; WT = WTk; C = kproj; bm_ = bk_m; bc_ = bk_c; bm = by * 128; }
    else          { A = qx; WT = WTq; C = qproj; bm_ = bq_m; bc_ = bq_c; bm = (by - 128) * 128; }
    const int bn = blockIdx.x * 128;
    f32x4 acc[4][4]; zero_acc(acc);
    mfma_nt_staged<16>(A, WT, KDIM, KDIM, bm, bn, As, Bs, acc);
    const int wv = threadIdx.x >> 6, ln = threadIdx.x & 63;
    const int r = ln & 15, quad = ln >> 4;
    const int m0 = bm + (wv >> 1) * 64, n0 = bn + (wv & 1) * 64;
    #pragma unroll
    for (int j = 0; j < 4; ++j) {
        const int n = n0 + j * 16 + r;
        const float bv = (n < 512) ? bm_[n] : bc_[n - 512];
        #pragma unroll
        for (int i = 0; i < 4; ++i) {
            #pragma unroll
            for (int reg = 0; reg < 4; ++reg) {
                const int m = m0 + i * 16 + quad * 4 + reg;
                C[(size_t)m * 1024 + n] = f2bf(acc[i][j][reg] + bv);
            }
        }
    }
}

// ---------------------------------------------------------------------------
// p_choose: per batch b, p = sigmoid(qm[b] @ km[b]^T / sqrt(512) + r + noise)
// ---------------------------------------------------------------------------
__global__ __launch_bounds__(256) void pchoose_mfma(
    const unsigned short* __restrict__ qp, const unsigned short* __restrict__ kp,
    const float* __restrict__ noise, const float* __restrict__ rp,
    float* __restrict__ p)
{
    __shared__ unsigned short As[128 * 32];
    __shared__ unsigned short Bs[128 * 32];
    const int b = blockIdx.z;
    const unsigned short* A = qp + (size_t)b * QLEN * 1024;
    const unsigned short* B = kp + (size_t)b * KLEN * 1024;
    const int bm = blockIdx.y * 128, bn = blockIdx.x * 128;
    f32x4 acc[4][4]; zero_acc(acc);
    mfma_nt_staged<16>(A, B, 1024, 1024, bm, bn, As, Bs, acc);
    const int wv = threadIdx.x >> 6, ln = threadIdx.x & 63;
    const int r = ln & 15, quad = ln >> 4;
    const int m0 = bm + (wv >> 1) * 64, n0 = bn + (wv & 1) * 64;
    const float rv = rp[0];
    #pragma unroll
    for (int i = 0; i < 4; ++i) {
        #pragma unroll
        for (int reg = 0; reg < 4; ++reg) {
            const int q = m0 + i * 16 + quad * 4 + reg;
            const size_t rowoff = ((size_t)b * QLEN + q) * KLEN;
            #pragma unroll
            for (int j = 0; j < 4; ++j) {
                const int k = n0 + j * 16 + r;
                const float e = acc[i][j][reg] * INV_SCALE + rv + noise[rowoff + k];
                p[rowoff + k] = __builtin_amdgcn_rcpf(1.0f + __expf(-e));
            }
        }
    }
}

// ---------------------------------------------------------------------------
// 64-lane inclusive prefix sum via DPP (≈6 VALU ops)
// ---------------------------------------------------------------------------
__device__ __forceinline__ float wave_incl_scan(float x)
{
#define DPP_ADD(ctrl, rmask, bctrl)                                            \
    { int _t = __builtin_amdgcn_update_dpp(0, __builtin_bit_cast(int, x),      \
                                           ctrl, rmask, 0xf, bctrl);           \
      x += __builtin_bit_cast(float, _t); }
    DPP_ADD(0x111, 0xf, true)   // row_shr:1
    DPP_ADD(0x112, 0xf, true)   // row_shr:2
    DPP_ADD(0x114, 0xf, true)   // row_shr:4
    DPP_ADD(0x118, 0xf, true)   // row_shr:8
    DPP_ADD(0x142, 0xa, false)  // row_bcast:15 -> rows 1,3
    DPP_ADD(0x143, 0xc, false)  // row_bcast:31 -> rows 2,3
#undef DPP_ADD
    return x;
}

// ---------------------------------------------------------------------------
// cumprod_mr: per (b,q) row: cp = exp(excl_cumsum(log(clip(1-p)))); emits
// m = p*cp, r = 1/clip(cp). Fast intrinsics; absorbs all transcendentals.
// ---------------------------------------------------------------------------
__global__ __launch_bounds__(256) void cumprod_mr(
    const float* __restrict__ p, float* __restrict__ mArr, float* __restrict__ rArr)
{
    const size_t row = blockIdx.x;
    const float* pr = p + row * KLEN;
    float* mr = mArr + row * KLEN;
    float* rr = rArr + row * KLEN;
    const int tid = threadIdx.x;
    const int lane = tid & 63, wid = tid >> 6;
    __shared__ float waveTot[4];

    float4 v0 = *(const float4*)(pr + tid * 8);
    float4 v1 = *(const float4*)(pr + tid * 8 + 4);
    float pv[8] = {v0.x, v0.y, v0.z, v0.w, v1.x, v1.y, v1.z, v1.w};
    float excl[8];
    float run = 0.0f;
    #pragma unroll
    for (int j = 0; j < 8; ++j) {
        float l = __logf(fminf(fmaxf(1.0f - pv[j], EPSV), 1.0f));
        excl[j] = run;
        run += l;
    }
    float s = wave_incl_scan(run);
    if (lane == 63) waveTot[wid] = s;
    __syncthreads();
    float wex = 0.0f;
    for (int w = 0; w < wid; ++w) wex += waveTot[w];
    const float texcl = wex + s - run;

    float mv[8], rv[8];
    #pragma unroll
    for (int j = 0; j < 8; ++j) {
        const float cpv = __expf(texcl + excl[j]);
        mv[j] = pv[j] * cpv;
        rv[j] = __builtin_amdgcn_rcpf(fminf(fmaxf(cpv, EPSV), 1.0f));
    }
    *(float4*)(mr + tid * 8)     = *(float4*)&mv[0];
    *(float4*)(mr + tid * 8 + 4) = *(float4*)&mv[4];
    *(float4*)(rr + tid * 8)     = *(float4*)&rv[0];
    *(float4*)(rr + tid * 8 + 4) = *(float4*)&rv[4];
}

// ---------------------------------------------------------------------------
// alpha_echunk: FUSED kernel, 256 threads (R5: was 512).
//  Blocks 0..7: 4-WAVE alpha recurrence (barrier structure proven in R0/R3;
//    R2 single-wave and R4 spin-pipeline both lost to it). 256 threads x
//    8 elems/lane. vs R3's 8-wave: chain is 8 fmaf (+~30cy) but the barrier
//    now syncs 4 waves instead of 8 (halved arrival jitter x256 steps) and
//    the cross-wave read-back is a single ds_read_b128 broadcast.
//  Blocks 8..1031: e_chunk MFMA tiles — these only ever used 256 worker
//    threads; the old waves 4..7 were dead weight marching through barriers.
//  smem stays 96 KB -> 1 block/CU (R3 isolation, +4% proven).
// ---------------------------------------------------------------------------
__global__ __launch_bounds__(256, 1) void alpha_echunk(
    const float* __restrict__ mArr, const float* __restrict__ rArr,
    float* __restrict__ alpha,
    const unsigned short* __restrict__ qp, const unsigned short* __restrict__ kp,
    float* __restrict__ out)
{
    __shared__ __align__(16) char smem[98304];   // 96 KB -> 1 block/CU
    const int bid = blockIdx.x;
    const int tid = threadIdx.x;

    if (bid < BATCH) {
        // ---------------- alpha scan: 4 waves, 8 elems/lane ----------------
        __builtin_amdgcn_s_setprio(1);
        float (*wt)[4] = (float (*)[4])smem;   // [2][4]
        const int lane = tid & 63, wid = tid >> 6;
        const float* mrow = mArr + (size_t)bid * QLEN * KLEN + tid * 8;
        const float* rrow = rArr + (size_t)bid * QLEN * KLEN + tid * 8;
        float* arow = alpha + (size_t)bid * QLEN * KLEN + tid * 8;

        float aw0 = 0.f, aw1 = 0.f, aw2 = 0.f, aw3 = 0.f;
        float aw4 = 0.f, aw5 = 0.f, aw6 = 0.f, aw7 = 0.f;
        if (tid == 0) aw0 = 1.0f;   // aw_prev one-hot at k=0

        float4 mA0 = *(const float4*)(mrow);
        float4 mA1 = *(const float4*)(mrow + 4);
        float4 rA0 = *(const float4*)(rrow);
        float4 rA1 = *(const float4*)(rrow + 4);
        float4 mB0 = *(const float4*)(mrow + KLEN);
        float4 mB1 = *(const float4*)(mrow + KLEN + 4);
        float4 rB0 = *(const float4*)(rrow + KLEN);
        float4 rB1 = *(const float4*)(rrow + KLEN + 4);

#define ASTEP(I, M0, M1, R0, R1)                                               \
    {                                                                          \
        const int i_ = (I);                                                    \
        float4 mc0 = M0, mc1 = M1, rc0 = R0, rc1 = R1;                         \
        const int rn_ = (i_ + 2 < QLEN) ? (i_ + 2) : (QLEN - 1);               \
        M0 = *(const float4*)(mrow + (size_t)rn_ * KLEN);                      \
        M1 = *(const float4*)(mrow + (size_t)rn_ * KLEN + 4);                  \
        R0 = *(const float4*)(rrow + (size_t)rn_ * KLEN);                      \
        R1 = *(const float4*)(rrow + (size_t)rn_ * KLEN + 4);                  \
        float run = 0.0f, i0, i1, i2, i3, i4, i5, i6, i7;                      \
        run = fmaf(aw0, rc0.x, run); i0 = run;                                 \
        run = fmaf(aw1, rc0.y, run); i1 = run;                                 \
        run = fmaf(aw2, rc0.z, run); i2 = run;                                 \
        run = fmaf(aw3, rc0.w, run); i3 = run;                                 \
        run = fmaf(aw4, rc1.x, run); i4 = run;                                 \
        run = fmaf(aw5, rc1.y, run); i5 = run;                                 \
        run = fmaf(aw6, rc1.z, run); i6 = run;                                 \
        run = fmaf(aw7, rc1.w, run); i7 = run;                                 \
        float tot = wave_incl_scan(run);                                       \
        if (lane == 63) wt[i_ & 1][wid] = tot;                                 \
        lds_barrier();                                                         \
        float base = tot - run;                                                \
        float4 w0 = *(const float4*)&wt[i_ & 1][0];                            \
        if (wid > 0) base += w0.x;                                             \
        if (wid > 1) base += w0.y;                                             \
        if (wid > 2) base += w0.z;                                             \
        aw0 = mc0.x * (base + i0);                                             \
        aw1 = mc0.y * (base + i1);                                             \
        aw2 = mc0.z * (base + i2);                                             \
        aw3 = mc0.w * (base + i3);                                             \
        aw4 = mc1.x * (base + i4);                                             \
        aw5 = mc1.y * (base + i5);                                             \
        aw6 = mc1.z * (base + i6);                                             \
        aw7 = mc1.w * (base + i7);                                             \
        float4 ov0; ov0.x = aw0; ov0.y = aw1; ov0.z = aw2; ov0.w = aw3;        \
        float4 ov1; ov1.x = aw4; ov1.y = aw5; ov1.z = aw6; ov1.w = aw7;        \
        *(float4*)(arow + (size_t)i_ * KLEN)     = ov0;                        \
        *(float4*)(arow + (size_t)i_ * KLEN + 4) = ov1;                        \
    }

        for (int io = 0; io < QLEN; io += 2) {
            ASTEP(io + 0, mA0, mA1, rA0, rA1)
            ASTEP(io + 1, mB0, mB1, rB0, rB1)
        }
#undef ASTEP
        __builtin_amdgcn_s_setprio(0);
        return;
    }

    // ---------------- echunk tile (256 threads, all workers) ----------------
    const int v = bid - BATCH;           // 0..1023
    const int z = v >> 5;                // 0..31 = b*4+h
    const int by = (v >> 4) & 1;
    const int bx = v & 15;
    const int b = z >> 2, h = z & 3;
    unsigned short* As = (unsigned short*)smem;            // 8 KB
    unsigned short* Bs = (unsigned short*)(smem + 8192);   // 8 KB
    const unsigned short* A = qp + (size_t)b * QLEN * 1024 + 512 + h * DKH;
    const unsigned short* B = kp + (size_t)b * KLEN * 1024 + 512 + h * DKH;
    const int bm = by * 128, bn = bx * 128;

    const int wv = tid >> 6, ln = tid & 63;
    const int r = ln & 15, quad = ln >> 4;
    const int wm = (wv >> 1) * 64, wn = (wv & 1) * 64;
    const int srow = wv * 16 + (ln >> 2);
    const int scol = (ln & 3) * 8;

    f32x4 acc[4][4]; zero_acc(acc);
    for (int ks = 0; ks < 4; ++ks) {
        const int k0 = ks * 32;
        #pragma unroll
        for (int j = 0; j < 2; ++j) {
            gload_lds16(A + (size_t)(bm + j * 64 + srow) * 1024 + k0 + scol,
                        As + (size_t)(j * 64 + wv * 16) * 32);
            gload_lds16(B + (size_t)(bn + j * 64 + srow) * 1024 + k0 + scol,
                        Bs + (size_t)(j * 64 + wv * 16) * 32);
        }
        __syncthreads();
        bf16x8 af[4], bg[4];
        #pragma unroll
        for (int f = 0; f < 4; ++f)
            af[f] = *(const bf16x8*)(As + (size_t)(wm + f * 16 + r) * 32 + quad * 8);
        #pragma unroll
        for (int f = 0; f < 4; ++f)
            bg[f] = *(const bf16x8*)(Bs + (size_t)(wn + f * 16 + r) * 32 + quad * 8);
        #pragma unroll
        for (int i = 0; i < 4; ++i)
            #pragma unroll
            for (int j2 = 0; j2 < 4; ++j2)
                acc[i][j2] = __builtin_amdgcn_mfma_f32_16x16x32_bf16(
                    af[i], bg[j2], acc[i][j2], 0, 0, 0);
        __syncthreads();
    }
    {
        const int m0 = bm + (wv >> 1) * 64, n0 = bn + (wv & 1) * 64;
        #pragma unroll
        for (int i = 0; i < 4; ++i) {
            #pragma unroll
            for (int reg = 0; reg < 4; ++reg) {
                const int q = m0 + i * 16 + quad * 4 + reg;
                const size_t rowoff = ((size_t)z * QLEN + q) * KLEN;
                #pragma unroll
                for (int j = 0; j < 4; ++j) {
                    const int k = n0 + j * 16 + r;
                    out[rowoff + k] = acc[i][j][reg] * INV_SCALE;
                }
            }
        }
    }
}

// ---------------------------------------------------------------------------
// beta: per (b,h,q) row of 2048 (e_chunk in d_out, overwritten)
// ---------------------------------------------------------------------------
__global__ __launch_bounds__(256) void beta_kernel(
    float* __restrict__ eo, const float* __restrict__ alpha)
{
    __shared__ float sse[KLEN + 3];
    __shared__ float su[KLEN + 3];
    __shared__ float wmax[4];

    const int tid = threadIdx.x;
    const int lane = tid & 63, wid = tid >> 6;
    const int row = blockIdx.x;                 // [B*H*Q]
    const int q = row & (QLEN - 1);
    const int b = row >> 10;
    float* erow = eo + (size_t)row * KLEN;
    const float* arow = alpha + ((size_t)b * QLEN + q) * KLEN;

    if (tid < 3) { sse[tid] = 0.0f; su[KLEN + tid] = 0.0f; }

    float ev[8];
    float lm = -INFINITY;
    #pragma unroll
    for (int j = 0; j < 8; ++j) {
        const int k = tid + 256 * j;
        ev[j] = erow[k];
        lm = fmaxf(lm, ev[j]);
    }
    #pragma unroll
    for (int off = 32; off > 0; off >>= 1) lm = fmaxf(lm, __shfl_xor(lm, off));
    if (lane == 0) wmax[wid] = lm;
    __syncthreads();
    const float mx = fmaxf(fmaxf(wmax[0], wmax[1]), fmaxf(wmax[2], wmax[3]));

    #pragma unroll
    for (int j = 0; j < 8; ++j) {
        const int k = tid + 256 * j;
        sse[k + 3] = fmaxf(__expf(ev[j] - mx), 1e-5f);
    }
    __syncthreads();

    #pragma unroll
    for (int j = 0; j < 8; ++j) {
        const int k = tid + 256 * j;
        const float denom = sse[k + 3] + sse[k + 2] + sse[k + 1] + sse[k];
        su[k] = arow[k] * __builtin_amdgcn_rcpf(denom);
    }
    __syncthreads();

    #pragma unroll
    for (int j = 0; j < 8; ++j) {
        const int k = tid + 256 * j;
        erow[k] = sse[k + 3] * (su[k] + su[k + 1] + su[k + 2] + su[k + 3]);
    }
}

// ---------------------------------------------------------------------------
extern "C" void kernel_launch(void* const* d_in, const int* in_sizes, int n_in,
                              void* d_out, int out_size, void* d_ws, size_t ws_size,
                              hipStream_t stream)
{
    (void)in_sizes; (void)n_in; (void)out_size; (void)ws_size;
    const float* key_enc = (const float*)d_in[0];   // [8,2048,512]
    const float* query   = (const float*)d_in[1];   // [8,256,512]
    const float* noise   = (const float*)d_in[2];   // [8,256,2048]
    const float* Wk_m    = (const float*)d_in[3];
    const float* bk_m    = (const float*)d_in[4];
    const float* Wq_m    = (const float*)d_in[5];
    const float* bq_m    = (const float*)d_in[6];
    const float* rp      = (const float*)d_in[7];
    const float* Wk_c    = (const float*)d_in[8];
    const float* bk_c    = (const float*)d_in[9];
    const float* Wq_c    = (const float*)d_in[10];
    const float* bq_c    = (const float*)d_in[11];
    float* out = (float*)d_out;                     // [8,4,256,2048]

    // workspace layout (bytes)
    char* w = (char*)d_ws;
    unsigned short* kx    = (unsigned short*)w; w += (size_t)BATCH * KLEN * KDIM * 2;   // 16.8 MB
    unsigned short* qx    = (unsigned short*)w; w += (size_t)BATCH * QLEN * KDIM * 2;   //  2.1 MB
    unsigned short* WTk   = (unsigned short*)w; w += (size_t)1024 * KDIM * 2;           //  1.0 MB
    unsigned short* WTq   = (unsigned short*)w; w += (size_t)1024 * KDIM * 2;           //  1.0 MB
    unsigned short* kproj = (unsigned short*)w; w += (size_t)BATCH * KLEN * 1024 * 2;   // 33.6 MB
    unsigned short* qproj = (unsigned short*)w; w += (size_t)BATCH * QLEN * 1024 * 2;   //  4.2 MB
    float* p_alpha = (float*)w; w += (size_t)BATCH * QLEN * KLEN * 4;                   // 16.8 MB
    float* mArr    = (float*)w; w += (size_t)BATCH * QLEN * KLEN * 4;                   // 16.8 MB
    float* rArr    = (float*)w;                                                         // 16.8 MB

    // 1) fused prep: casts + weight transposes (1 launch, was 6)
    hipLaunchKernelGGL(prep, dim3(NKXB + NQXB + 1024), dim3(256), 0, stream,
                       key_enc, query, Wk_m, Wk_c, Wq_m, Wq_c,
                       kx, qx, WTk, WTq);

    // 2) projections, k+q merged (1 launch, was 2)
    hipLaunchKernelGGL(proj_mfma, dim3(8, BATCH * KLEN / 128 + BATCH * QLEN / 128),
                       dim3(256), 0, stream,
                       kx, qx, WTk, WTq, bk_m, bk_c, bq_m, bq_c, kproj, qproj);

    // 3) p_choose (staged bf16 MFMA + fast sigmoid epilogue)
    hipLaunchKernelGGL(pchoose_mfma, dim3(KLEN / 128, QLEN / 128, BATCH), dim3(256), 0, stream,
                       qproj, kproj, noise, rp, p_alpha);

    // 4) cumprod -> (m, r)  (parallel, absorbs all transcendentals)
    hipLaunchKernelGGL(cumprod_mr, dim3(BATCH * QLEN), dim3(256), 0, stream,
                       p_alpha, mArr, rArr);

    // 5) FUSED: alpha recurrence (blocks 0..7, 4-wave) + e_chunk (blocks 8..1031)
    hipLaunchKernelGGL(alpha_echunk, dim3(BATCH + KLEN / 128 * QLEN / 128 * BATCH * NHEADS),
                       dim3(256), 0, stream,
                       mArr, rArr, p_alpha, qproj, kproj, out);

    // 6) beta (overwrites e_chunk rows in d_out)
    hipLaunchKernelGGL(beta_kernel, dim3(BATCH * NHEADS * QLEN), dim3(256), 0, stream,
                       out, p_alpha);
}